// Round 1
// baseline (24192.233 us; speedup 1.0000x reference)
//
#include <hip/hip_runtime.h>

// LSTM scan, persistent kernel.
// T=512, B=64, D=256, H=512, K = H+D = 768.
// 4 groups x 64 blocks (256 blocks, 1/CU). Group g owns batches [16g,16g+16).
// Block owns 8 hidden units (32 gate rows: [i f g o] x 8 units).
// Weights live in registers: thread (p,bh,kc) holds rows {2p,2p+1} cols [96kc,96kc+96).
// Per step: stage v=[h|x] in LDS -> reg-tiled f32 matmul -> shfl+LDS reduce ->
// elementwise -> write h to d_out (allhidden is the h history) -> group barrier.

#define TSTEPS 512
#define BATCH 64
#define DIN 256
#define HID 512
#define KTOT (HID + DIN)     // 768
#define BPG 64               // blocks per group
#define BPB 16               // batches per group
#define UPB 8                // units per block
#define VSTRIDE 772          // padded floats per v row (16B aligned, bank-spread)
#define KCHUNK 96
#define RSTRIDE 17           // padded batch dim for reduction buffer

__global__ __launch_bounds__(256, 1)
void lstm_persistent(const float* __restrict__ seqs,
                     const float* __restrict__ h0,
                     const float* __restrict__ c0,
                     const float* __restrict__ Wi, const float* __restrict__ bi,
                     const float* __restrict__ Wf, const float* __restrict__ bff,
                     const float* __restrict__ Wg, const float* __restrict__ bg,
                     const float* __restrict__ Wo, const float* __restrict__ bo,
                     float* __restrict__ out,          // [T+1][B][H] then cT [B][H]
                     unsigned int* __restrict__ bar)   // 4 counters, 256B apart
{
    __shared__ float v[BPB * VSTRIDE];            // 49408 B
    __shared__ float red[4 * 32 * RSTRIDE];       // 8704 B
    __shared__ float c_s[UPB * BPB];              // 512 B
    __shared__ float bias_s[32];                  // 128 B

    const int tid = threadIdx.x;
    const int bid = blockIdx.x;
    // group = XCD-pair for h-broadcast L2 locality
    const int g    = (bid & 7) >> 1;                    // 0..3
    const int rblk = ((bid & 1) << 5) | (bid >> 3);     // 0..63
    const int b0 = g * BPB;
    const int u0 = rblk * UPB;

    const int p  = tid & 15;        // row pair: rows 2p, 2p+1 (row = gate*8 + ulocal)
    const int bh = (tid >> 4) & 1;  // batch parity (batch = 2j + bh)
    const int kc = tid >> 5;        // k-chunk 0..7

    // ---- weight rows -> registers (once) ----
    const int m0   = 2 * p;
    const int gate = m0 >> 3;
    const int ul0  = m0 & 7;
    const float* Wsel = (gate == 0) ? Wi : (gate == 1) ? Wf : (gate == 2) ? Wg : Wo;
    const float* r0p = Wsel + (size_t)(u0 + ul0) * KTOT + kc * KCHUNK;
    const float* r1p = r0p + KTOT;   // next unit, same gate
    float4 wA[24], wB[24];
#pragma unroll
    for (int i = 0; i < 24; ++i) {
        wA[i] = reinterpret_cast<const float4*>(r0p)[i];
        wB[i] = reinterpret_cast<const float4*>(r1p)[i];
    }

    if (tid < 32) {
        const int gg = tid >> 3, uu = tid & 7;
        const float* bsel = (gg == 0) ? bi : (gg == 1) ? bff : (gg == 2) ? bg : bo;
        bias_s[tid] = bsel[u0 + uu];
    }
    if (tid < 128) {   // c init + allhidden[0] = h0
        const int uu = tid & 7, bb = tid >> 3;
        c_s[uu * BPB + bb] = c0[(size_t)(b0 + bb) * HID + u0 + uu];
        out[(size_t)(b0 + bb) * HID + u0 + uu] = h0[(size_t)(b0 + bb) * HID + u0 + uu];
    }

    for (int t = 0; t < TSTEPS; ++t) {
        // ---- stage v = [h_t | x_t] for this group's 16 batches ----
        const float* hsrc = (t == 0) ? h0 : (out + (size_t)t * BATCH * HID);
#pragma unroll
        for (int i = 0; i < 8; ++i) {
            const int idx = tid + i * 256;
            const int b = idx >> 7, k4 = idx & 127;     // 128 float4 per h row
            const float4 val =
                reinterpret_cast<const float4*>(hsrc + (size_t)(b0 + b) * HID)[k4];
            *reinterpret_cast<float4*>(&v[b * VSTRIDE + k4 * 4]) = val;
        }
        const float* xsrc = seqs + (size_t)t * BATCH * DIN;
#pragma unroll
        for (int i = 0; i < 4; ++i) {
            const int idx = tid + i * 256;
            const int b = idx >> 6, k4 = idx & 63;      // 64 float4 per x row
            const float4 val =
                reinterpret_cast<const float4*>(xsrc + (size_t)(b0 + b) * DIN)[k4];
            *reinterpret_cast<float4*>(&v[b * VSTRIDE + HID + k4 * 4]) = val;
        }
        __syncthreads();

        // ---- matmul: rows {2p,2p+1} x batches {2j+bh} over k-chunk kc ----
        float acc0[8], acc1[8];
#pragma unroll
        for (int j = 0; j < 8; ++j) { acc0[j] = 0.f; acc1[j] = 0.f; }
#pragma unroll
        for (int i4 = 0; i4 < 24; ++i4) {
            const float4 w0 = wA[i4];
            const float4 w1 = wB[i4];
#pragma unroll
            for (int j = 0; j < 8; ++j) {
                const float4 vv = *reinterpret_cast<const float4*>(
                    &v[(2 * j + bh) * VSTRIDE + kc * KCHUNK + i4 * 4]);
                acc0[j] = fmaf(w0.x, vv.x, acc0[j]);
                acc0[j] = fmaf(w0.y, vv.y, acc0[j]);
                acc0[j] = fmaf(w0.z, vv.z, acc0[j]);
                acc0[j] = fmaf(w0.w, vv.w, acc0[j]);
                acc1[j] = fmaf(w1.x, vv.x, acc1[j]);
                acc1[j] = fmaf(w1.y, vv.y, acc1[j]);
                acc1[j] = fmaf(w1.z, vv.z, acc1[j]);
                acc1[j] = fmaf(w1.w, vv.w, acc1[j]);
            }
        }

        // ---- reduce kc pairs in-wave, then 4 wave-partials via LDS ----
#pragma unroll
        for (int j = 0; j < 8; ++j) {
            acc0[j] += __shfl_xor(acc0[j], 32);
            acc1[j] += __shfl_xor(acc1[j], 32);
        }
        if ((kc & 1) == 0) {
            const int w = kc >> 1;   // == wave id
#pragma unroll
            for (int j = 0; j < 8; ++j) {
                red[(w * 32 + m0) * RSTRIDE + 2 * j + bh]     = acc0[j];
                red[(w * 32 + m0 + 1) * RSTRIDE + 2 * j + bh] = acc1[j];
            }
        }
        __syncthreads();

        // ---- elementwise gates + state update ----
        if (tid < 128) {
            const int uu = tid & 7, bb = tid >> 3;
            float gi = bias_s[uu], gf = bias_s[8 + uu],
                  gG = bias_s[16 + uu], go = bias_s[24 + uu];
#pragma unroll
            for (int w = 0; w < 4; ++w) {
                gi += red[(w * 32 + uu) * RSTRIDE + bb];
                gf += red[(w * 32 + 8 + uu) * RSTRIDE + bb];
                gG += red[(w * 32 + 16 + uu) * RSTRIDE + bb];
                go += red[(w * 32 + 24 + uu) * RSTRIDE + bb];
            }
            const float i_ = 1.f / (1.f + __expf(-gi));
            const float f_ = 1.f / (1.f + __expf(-gf));
            const float o_ = 1.f / (1.f + __expf(-go));
            float eg = __expf(-2.f * fabsf(gG));
            float tg = (1.f - eg) / (1.f + eg);
            tg = (gG < 0.f) ? -tg : tg;
            const float cn = f_ * c_s[uu * BPB + bb] + i_ * tg;
            c_s[uu * BPB + bb] = cn;
            float ec = __expf(-2.f * fabsf(cn));
            float tc = (1.f - ec) / (1.f + ec);
            tc = (cn < 0.f) ? -tc : tc;
            const float hn = o_ * tc;
            out[(size_t)(t + 1) * BATCH * HID + (size_t)(b0 + bb) * HID + u0 + uu] = hn;
            if (t == TSTEPS - 1)
                out[(size_t)(TSTEPS + 1) * BATCH * HID + (size_t)(b0 + bb) * HID + u0 + uu] = cn;
        }

        // ---- group barrier (monotonic counter, release/acquire) ----
        __threadfence();          // release this thread's h stores device-wide
        __syncthreads();
        if (tid == 0) {
            atomicAdd(&bar[g * 64], 1u);
            const unsigned int target = (unsigned int)(t + 1) * BPG;
            while (__hip_atomic_load(&bar[g * 64], __ATOMIC_ACQUIRE,
                                     __HIP_MEMORY_SCOPE_AGENT) < target) {
                __builtin_amdgcn_s_sleep(4);
            }
        }
        __syncthreads();
        __threadfence();          // acquire before reading peers' h next step
    }
}

extern "C" void kernel_launch(void* const* d_in, const int* in_sizes, int n_in,
                              void* d_out, int out_size, void* d_ws, size_t ws_size,
                              hipStream_t stream) {
    const float* seqs = (const float*)d_in[0];
    const float* h0   = (const float*)d_in[1];
    const float* c0   = (const float*)d_in[2];
    const float* Wi   = (const float*)d_in[3];
    const float* bi   = (const float*)d_in[4];
    const float* Wf   = (const float*)d_in[5];
    const float* bf   = (const float*)d_in[6];
    const float* Wg   = (const float*)d_in[7];
    const float* bg   = (const float*)d_in[8];
    const float* Wo   = (const float*)d_in[9];
    const float* bo   = (const float*)d_in[10];
    float* out = (float*)d_out;
    unsigned int* bar = (unsigned int*)d_ws;

    // zero barrier counters every launch (deterministic across graph replays)
    hipMemsetAsync(bar, 0, 4 * 64 * sizeof(unsigned int), stream);

    hipLaunchKernelGGL(lstm_persistent, dim3(256), dim3(256), 0, stream,
                       seqs, h0, c0, Wi, bi, Wf, bf, Wg, bg, Wo, bo, out, bar);
}

// Round 3
// 7510.633 us; speedup vs baseline: 3.2211x; 3.2211x over previous
//
#include <hip/hip_runtime.h>

// LSTM scan, persistent kernel. T=512, B=64, D=256, H=512, K=768.
// 4 groups x 64 blocks. Group g owns batches [16g,16g+16). Block owns 8 hidden
// units (32 gate rows). Weights register-resident.
// Sync: h stores write-through to LLC (agent relaxed atomic store, sc0 sc1);
// vmcnt(0); relaxed arrival add into 8 spread counters; RELAXED poll (cheap);
// one ACQUIRE load on success (single buffer_inv per block per step) makes the
// next step's plain h loads coherent. Bounded spin + periodic rescue acquire:
// cannot deadlock.

#define TSTEPS 512
#define BATCH 64
#define DIN 256
#define HID 512
#define KTOT (HID + DIN)     // 768
#define BPG 64               // blocks per group
#define BPB 16               // batches per group
#define UPB 8                // units per block
#define VSTRIDE 772          // padded floats per v row
#define KCHUNK 96
#define RSTRIDE 17           // padded batch dim for reduction buffer

__global__ __launch_bounds__(256, 1)
void lstm_persistent(const float* __restrict__ seqs,
                     const float* __restrict__ h0,
                     const float* __restrict__ c0,
                     const float* __restrict__ Wi, const float* __restrict__ bi,
                     const float* __restrict__ Wf, const float* __restrict__ bff,
                     const float* __restrict__ Wg, const float* __restrict__ bg,
                     const float* __restrict__ Wo, const float* __restrict__ bo,
                     float* __restrict__ out,          // [T+1][B][H] then cT [B][H]
                     unsigned int* __restrict__ bar)   // 4 groups x 8 counters, 128B apart
{
    __shared__ float v[BPB * VSTRIDE];            // 49408 B
    __shared__ float red[4 * 32 * RSTRIDE];       // 8704 B
    __shared__ float c_s[UPB * BPB];              // 512 B
    __shared__ float bias_s[32];                  // 128 B

    const int tid = threadIdx.x;
    const int bid = blockIdx.x;
    const int g    = (bid & 7) >> 1;                    // group 0..3 (XCD pair)
    const int rblk = ((bid & 1) << 5) | (bid >> 3);     // 0..63 within group
    const int sub  = (bid >> 3) & 7;                    // arrival sub-counter
    const int b0 = g * BPB;
    const int u0 = rblk * UPB;

    const int p  = tid & 15;        // row pair: rows 2p, 2p+1 (row = gate*8 + ulocal)
    const int bh = (tid >> 4) & 1;  // batch parity (batch = 2j + bh)
    const int kc = tid >> 5;        // k-chunk 0..7

    // ---- weight rows -> registers (once) ----
    const int m0   = 2 * p;
    const int gate = m0 >> 3;
    const int ul0  = m0 & 7;
    const float* Wsel = (gate == 0) ? Wi : (gate == 1) ? Wf : (gate == 2) ? Wg : Wo;
    const float* r0p = Wsel + (size_t)(u0 + ul0) * KTOT + kc * KCHUNK;
    const float* r1p = r0p + KTOT;   // next unit, same gate
    float4 wA[24], wB[24];
#pragma unroll
    for (int i = 0; i < 24; ++i) {
        wA[i] = reinterpret_cast<const float4*>(r0p)[i];
        wB[i] = reinterpret_cast<const float4*>(r1p)[i];
    }

    if (tid < 32) {
        const int gg = tid >> 3, uu = tid & 7;
        const float* bsel = (gg == 0) ? bi : (gg == 1) ? bff : (gg == 2) ? bg : bo;
        bias_s[tid] = bsel[u0 + uu];
    }
    if (tid < 128) {   // c init + allhidden[0] = h0
        const int uu = tid & 7, bb = tid >> 3;
        c_s[uu * BPB + bb] = c0[(size_t)(b0 + bb) * HID + u0 + uu];
        out[(size_t)(b0 + bb) * HID + u0 + uu] = h0[(size_t)(b0 + bb) * HID + u0 + uu];
    }

    // ---- prefetch x_0 into LDS x-slot ----
    {
        const float* xsrc = seqs;   // t = 0
#pragma unroll
        for (int i = 0; i < 4; ++i) {
            const int idx = tid + i * 256;
            const int b = idx >> 6, k4 = idx & 63;
            const float4 val =
                reinterpret_cast<const float4*>(xsrc + (size_t)(b0 + b) * DIN)[k4];
            *reinterpret_cast<float4*>(&v[b * VSTRIDE + HID + k4 * 4]) = val;
        }
    }

    for (int t = 0; t < TSTEPS; ++t) {
        // ---- stage h_t: plain float4 loads (caches were acquire-invalidated
        //      at the end of the previous step, so these see fresh LLC data) ----
        {
            const float* hsrc = (t == 0) ? h0 : (out + (size_t)t * BATCH * HID);
#pragma unroll
            for (int i = 0; i < 8; ++i) {
                const int idx = tid + i * 256;
                const int b = idx >> 7, k4 = idx & 127;     // 128 float4 per h row
                const float4 val =
                    reinterpret_cast<const float4*>(hsrc + (size_t)(b0 + b) * HID)[k4];
                *reinterpret_cast<float4*>(&v[b * VSTRIDE + k4 * 4]) = val;
            }
        }
        __syncthreads();

        // ---- matmul: rows {2p,2p+1} x batches {2j+bh} over k-chunk kc ----
        float acc0[8], acc1[8];
#pragma unroll
        for (int j = 0; j < 8; ++j) { acc0[j] = 0.f; acc1[j] = 0.f; }
#pragma unroll
        for (int i4 = 0; i4 < 24; ++i4) {
            const float4 w0 = wA[i4];
            const float4 w1 = wB[i4];
#pragma unroll
            for (int j = 0; j < 8; ++j) {
                const float4 vv = *reinterpret_cast<const float4*>(
                    &v[(2 * j + bh) * VSTRIDE + kc * KCHUNK + i4 * 4]);
                acc0[j] = fmaf(w0.x, vv.x, acc0[j]);
                acc0[j] = fmaf(w0.y, vv.y, acc0[j]);
                acc0[j] = fmaf(w0.z, vv.z, acc0[j]);
                acc0[j] = fmaf(w0.w, vv.w, acc0[j]);
                acc1[j] = fmaf(w1.x, vv.x, acc1[j]);
                acc1[j] = fmaf(w1.y, vv.y, acc1[j]);
                acc1[j] = fmaf(w1.z, vv.z, acc1[j]);
                acc1[j] = fmaf(w1.w, vv.w, acc1[j]);
            }
        }

        // ---- reduce kc pairs in-wave, then 4 wave-partials via LDS ----
#pragma unroll
        for (int j = 0; j < 8; ++j) {
            acc0[j] += __shfl_xor(acc0[j], 32);
            acc1[j] += __shfl_xor(acc1[j], 32);
        }
        if ((kc & 1) == 0) {
            const int w = kc >> 1;
#pragma unroll
            for (int j = 0; j < 8; ++j) {
                red[(w * 32 + m0) * RSTRIDE + 2 * j + bh]     = acc0[j];
                red[(w * 32 + m0 + 1) * RSTRIDE + 2 * j + bh] = acc1[j];
            }
        }
        __syncthreads();

        // ---- elementwise gates + state update; h store is write-through atomic ----
        if (tid < 128) {
            const int uu = tid & 7, bb = tid >> 3;
            float gi = bias_s[uu], gf = bias_s[8 + uu],
                  gG = bias_s[16 + uu], go = bias_s[24 + uu];
#pragma unroll
            for (int w = 0; w < 4; ++w) {
                gi += red[(w * 32 + uu) * RSTRIDE + bb];
                gf += red[(w * 32 + 8 + uu) * RSTRIDE + bb];
                gG += red[(w * 32 + 16 + uu) * RSTRIDE + bb];
                go += red[(w * 32 + 24 + uu) * RSTRIDE + bb];
            }
            const float i_ = 1.f / (1.f + __expf(-gi));
            const float f_ = 1.f / (1.f + __expf(-gf));
            const float o_ = 1.f / (1.f + __expf(-go));
            float eg = __expf(-2.f * fabsf(gG));
            float tg = (1.f - eg) / (1.f + eg);
            tg = (gG < 0.f) ? -tg : tg;
            const float cn = f_ * c_s[uu * BPB + bb] + i_ * tg;
            c_s[uu * BPB + bb] = cn;
            float ec = __expf(-2.f * fabsf(cn));
            float tc = (1.f - ec) / (1.f + ec);
            tc = (cn < 0.f) ? -tc : tc;
            const float hn = o_ * tc;
            __hip_atomic_store(
                out + (size_t)(t + 1) * BATCH * HID + (size_t)(b0 + bb) * HID + u0 + uu,
                hn, __ATOMIC_RELAXED, __HIP_MEMORY_SCOPE_AGENT);
            if (t == TSTEPS - 1)
                out[(size_t)(TSTEPS + 1) * BATCH * HID + (size_t)(b0 + bb) * HID + u0 + uu] = cn;
        }

        // ---- prefetch x_{t+1} into LDS BEFORE the barrier/invalidate ----
        if (t + 1 < TSTEPS) {
            const float* xsrc = seqs + (size_t)(t + 1) * BATCH * DIN;
#pragma unroll
            for (int i = 0; i < 4; ++i) {
                const int idx = tid + i * 256;
                const int b = idx >> 6, k4 = idx & 63;
                const float4 val =
                    reinterpret_cast<const float4*>(xsrc + (size_t)(b0 + b) * DIN)[k4];
                *reinterpret_cast<float4*>(&v[b * VSTRIDE + HID + k4 * 4]) = val;
            }
        }

        // ---- group barrier: drain h stores, arrive, relaxed poll, acquire exit ----
        asm volatile("s_waitcnt vmcnt(0)" ::: "memory");  // h stores at LLC
        __syncthreads();                                   // whole block drained
        if (tid == 0) {
            __hip_atomic_fetch_add(&bar[(g * 8 + sub) * 32], 1u,
                                   __ATOMIC_RELAXED, __HIP_MEMORY_SCOPE_AGENT);
            const unsigned int target = (unsigned int)(t + 1) * BPG;
            unsigned int miss = 0;
            for (;;) {
                unsigned int s = 0;
#pragma unroll
                for (int i = 0; i < 8; ++i)
                    s += __hip_atomic_load(&bar[(g * 8 + i) * 32],
                                           __ATOMIC_RELAXED, __HIP_MEMORY_SCOPE_AGENT);
                if (s >= target) break;
                ++miss;
                if ((miss & 2047) == 0) {   // rescue: force cache refresh
                    (void)__hip_atomic_load(&bar[(g * 8) * 32],
                                            __ATOMIC_ACQUIRE, __HIP_MEMORY_SCOPE_AGENT);
                }
                if (miss > (1u << 20)) break;  // bounded: never hang the GPU
                __builtin_amdgcn_s_sleep(4);
            }
            // acquire: invalidate L1/L2 so next step's plain h loads are fresh
            (void)__hip_atomic_load(&bar[(g * 8) * 32],
                                    __ATOMIC_ACQUIRE, __HIP_MEMORY_SCOPE_AGENT);
        }
        __syncthreads();
    }
}

extern "C" void kernel_launch(void* const* d_in, const int* in_sizes, int n_in,
                              void* d_out, int out_size, void* d_ws, size_t ws_size,
                              hipStream_t stream) {
    const float* seqs = (const float*)d_in[0];
    const float* h0   = (const float*)d_in[1];
    const float* c0   = (const float*)d_in[2];
    const float* Wi   = (const float*)d_in[3];
    const float* bi   = (const float*)d_in[4];
    const float* Wf   = (const float*)d_in[5];
    const float* bf   = (const float*)d_in[6];
    const float* Wg   = (const float*)d_in[7];
    const float* bg   = (const float*)d_in[8];
    const float* Wo   = (const float*)d_in[9];
    const float* bo   = (const float*)d_in[10];
    float* out = (float*)d_out;
    unsigned int* bar = (unsigned int*)d_ws;

    // zero barrier counters every launch (deterministic across graph replays)
    hipMemsetAsync(bar, 0, 4 * 8 * 32 * sizeof(unsigned int), stream);

    hipLaunchKernelGGL(lstm_persistent, dim3(256), dim3(256), 0, stream,
                       seqs, h0, c0, Wi, bi, Wf, bf, Wg, bg, Wo, bo, out, bar);
}

// Round 4
// 6133.210 us; speedup vs baseline: 3.9445x; 1.2246x over previous
//
#include <hip/hip_runtime.h>

// LSTM scan, persistent kernel. T=512, B=64, D=256, H=512, K=768.
// 4 groups x 64 blocks. Group g owns batches [16g,16g+16). Block owns 8 hidden
// units (32 gate rows). Weights register-resident.
// Sync (R4): ZERO acquire/invalidate ops. h stores write-through to LLC
// (agent relaxed atomic store -> sc0 sc1); h loads are inline-asm
// global_load_dwordx4 sc0 sc1 (LLC-direct, no L2 invalidate). Barrier =
// vmcnt(0) + relaxed fetch_add into 8 spread counters + relaxed bounded poll.
// L2 stays warm for x/weights; coherence point is the LLC only.

#define TSTEPS 512
#define BATCH 64
#define DIN 256
#define HID 512
#define KTOT (HID + DIN)     // 768
#define BPG 64               // blocks per group
#define BPB 16               // batches per group
#define UPB 8                // units per block
#define VSTRIDE 772          // padded floats per v row
#define KCHUNK 96
#define RSTRIDE 17           // padded batch dim for reduction buffer

// LLC-coherent 16B load: bypasses L1 and (non-coherent) L2, reads LLC.
__device__ __forceinline__ float4 llc_load4(const float* p) {
    float4 r;
    asm volatile("global_load_dwordx4 %0, %1, off sc0 sc1"
                 : "=v"(r) : "v"(p));
    return r;
}

__global__ __launch_bounds__(256, 1)
void lstm_persistent(const float* __restrict__ seqs,
                     const float* __restrict__ h0,
                     const float* __restrict__ c0,
                     const float* __restrict__ Wi, const float* __restrict__ bi,
                     const float* __restrict__ Wf, const float* __restrict__ bff,
                     const float* __restrict__ Wg, const float* __restrict__ bg,
                     const float* __restrict__ Wo, const float* __restrict__ bo,
                     float* __restrict__ out,          // [T+1][B][H] then cT [B][H]
                     unsigned int* __restrict__ bar)   // 4 groups x 8 counters, 128B apart
{
    __shared__ float v[BPB * VSTRIDE];            // 49408 B
    __shared__ float red[4 * 32 * RSTRIDE];       // 8704 B
    __shared__ float c_s[UPB * BPB];              // 512 B
    __shared__ float bias_s[32];                  // 128 B

    const int tid = threadIdx.x;
    const int bid = blockIdx.x;
    const int g    = (bid & 7) >> 1;                    // group 0..3 (XCD pair)
    const int rblk = ((bid & 1) << 5) | (bid >> 3);     // 0..63 within group
    const int sub  = (bid >> 3) & 7;                    // arrival sub-counter
    const int b0 = g * BPB;
    const int u0 = rblk * UPB;

    const int p  = tid & 15;        // row pair: rows 2p, 2p+1 (row = gate*8 + ulocal)
    const int bh = (tid >> 4) & 1;  // batch parity (batch = 2j + bh)
    const int kc = tid >> 5;        // k-chunk 0..7

    // ---- weight rows -> registers (once) ----
    const int m0   = 2 * p;
    const int gate = m0 >> 3;
    const int ul0  = m0 & 7;
    const float* Wsel = (gate == 0) ? Wi : (gate == 1) ? Wf : (gate == 2) ? Wg : Wo;
    const float* r0p = Wsel + (size_t)(u0 + ul0) * KTOT + kc * KCHUNK;
    const float* r1p = r0p + KTOT;   // next unit, same gate
    float4 wA[24], wB[24];
#pragma unroll
    for (int i = 0; i < 24; ++i) {
        wA[i] = reinterpret_cast<const float4*>(r0p)[i];
        wB[i] = reinterpret_cast<const float4*>(r1p)[i];
    }

    if (tid < 32) {
        const int gg = tid >> 3, uu = tid & 7;
        const float* bsel = (gg == 0) ? bi : (gg == 1) ? bff : (gg == 2) ? bg : bo;
        bias_s[tid] = bsel[u0 + uu];
    }
    if (tid < 128) {   // c init + allhidden[0] = h0
        const int uu = tid & 7, bb = tid >> 3;
        c_s[uu * BPB + bb] = c0[(size_t)(b0 + bb) * HID + u0 + uu];
        out[(size_t)(b0 + bb) * HID + u0 + uu] = h0[(size_t)(b0 + bb) * HID + u0 + uu];
    }

    // ---- prefetch x_0 into LDS x-slot (plain cached loads) ----
    {
        const float* xsrc = seqs;   // t = 0
#pragma unroll
        for (int i = 0; i < 4; ++i) {
            const int idx = tid + i * 256;
            const int b = idx >> 6, k4 = idx & 63;
            const float4 val =
                reinterpret_cast<const float4*>(xsrc + (size_t)(b0 + b) * DIN)[k4];
            *reinterpret_cast<float4*>(&v[b * VSTRIDE + HID + k4 * 4]) = val;
        }
    }

    for (int t = 0; t < TSTEPS; ++t) {
        // ---- stage h_t: LLC-direct bypass loads (no invalidate needed) ----
        {
            const float* hsrc = (t == 0) ? h0 : (out + (size_t)t * BATCH * HID);
            float4 hbuf[8];
#pragma unroll
            for (int i = 0; i < 8; ++i) {
                const int idx = tid + i * 256;
                const int b = idx >> 7, k4 = idx & 127;     // 128 float4 per h row
                hbuf[i] = llc_load4(hsrc + (size_t)(b0 + b) * HID + k4 * 4);
            }
            asm volatile("s_waitcnt vmcnt(0)" ::: "memory");
            __builtin_amdgcn_sched_barrier(0);
#pragma unroll
            for (int i = 0; i < 8; ++i) {
                const int idx = tid + i * 256;
                const int b = idx >> 7, k4 = idx & 127;
                *reinterpret_cast<float4*>(&v[b * VSTRIDE + k4 * 4]) = hbuf[i];
            }
        }
        __syncthreads();

        // ---- matmul: rows {2p,2p+1} x batches {2j+bh} over k-chunk kc ----
        float acc0[8], acc1[8];
#pragma unroll
        for (int j = 0; j < 8; ++j) { acc0[j] = 0.f; acc1[j] = 0.f; }
#pragma unroll
        for (int i4 = 0; i4 < 24; ++i4) {
            const float4 w0 = wA[i4];
            const float4 w1 = wB[i4];
#pragma unroll
            for (int j = 0; j < 8; ++j) {
                const float4 vv = *reinterpret_cast<const float4*>(
                    &v[(2 * j + bh) * VSTRIDE + kc * KCHUNK + i4 * 4]);
                acc0[j] = fmaf(w0.x, vv.x, acc0[j]);
                acc0[j] = fmaf(w0.y, vv.y, acc0[j]);
                acc0[j] = fmaf(w0.z, vv.z, acc0[j]);
                acc0[j] = fmaf(w0.w, vv.w, acc0[j]);
                acc1[j] = fmaf(w1.x, vv.x, acc1[j]);
                acc1[j] = fmaf(w1.y, vv.y, acc1[j]);
                acc1[j] = fmaf(w1.z, vv.z, acc1[j]);
                acc1[j] = fmaf(w1.w, vv.w, acc1[j]);
            }
        }

        // ---- reduce kc pairs in-wave, then 4 wave-partials via LDS ----
#pragma unroll
        for (int j = 0; j < 8; ++j) {
            acc0[j] += __shfl_xor(acc0[j], 32);
            acc1[j] += __shfl_xor(acc1[j], 32);
        }
        if ((kc & 1) == 0) {
            const int w = kc >> 1;
#pragma unroll
            for (int j = 0; j < 8; ++j) {
                red[(w * 32 + m0) * RSTRIDE + 2 * j + bh]     = acc0[j];
                red[(w * 32 + m0 + 1) * RSTRIDE + 2 * j + bh] = acc1[j];
            }
        }
        __syncthreads();

        // ---- elementwise gates + state update; h store is write-through atomic ----
        if (tid < 128) {
            const int uu = tid & 7, bb = tid >> 3;
            float gi = bias_s[uu], gf = bias_s[8 + uu],
                  gG = bias_s[16 + uu], go = bias_s[24 + uu];
#pragma unroll
            for (int w = 0; w < 4; ++w) {
                gi += red[(w * 32 + uu) * RSTRIDE + bb];
                gf += red[(w * 32 + 8 + uu) * RSTRIDE + bb];
                gG += red[(w * 32 + 16 + uu) * RSTRIDE + bb];
                go += red[(w * 32 + 24 + uu) * RSTRIDE + bb];
            }
            const float i_ = 1.f / (1.f + __expf(-gi));
            const float f_ = 1.f / (1.f + __expf(-gf));
            const float o_ = 1.f / (1.f + __expf(-go));
            float eg = __expf(-2.f * fabsf(gG));
            float tg = (1.f - eg) / (1.f + eg);
            tg = (gG < 0.f) ? -tg : tg;
            const float cn = f_ * c_s[uu * BPB + bb] + i_ * tg;
            c_s[uu * BPB + bb] = cn;
            float ec = __expf(-2.f * fabsf(cn));
            float tc = (1.f - ec) / (1.f + ec);
            tc = (cn < 0.f) ? -tc : tc;
            const float hn = o_ * tc;
            __hip_atomic_store(
                out + (size_t)(t + 1) * BATCH * HID + (size_t)(b0 + bb) * HID + u0 + uu,
                hn, __ATOMIC_RELAXED, __HIP_MEMORY_SCOPE_AGENT);
            if (t == TSTEPS - 1)
                out[(size_t)(TSTEPS + 1) * BATCH * HID + (size_t)(b0 + bb) * HID + u0 + uu] = cn;
        }

        // ---- prefetch x_{t+1} into LDS (plain cached loads, L2 stays warm) ----
        if (t + 1 < TSTEPS) {
            const float* xsrc = seqs + (size_t)(t + 1) * BATCH * DIN;
#pragma unroll
            for (int i = 0; i < 4; ++i) {
                const int idx = tid + i * 256;
                const int b = idx >> 6, k4 = idx & 63;
                const float4 val =
                    reinterpret_cast<const float4*>(xsrc + (size_t)(b0 + b) * DIN)[k4];
                *reinterpret_cast<float4*>(&v[b * VSTRIDE + HID + k4 * 4]) = val;
            }
        }

        // ---- group barrier: drain h stores, arrive, relaxed bounded poll ----
        asm volatile("s_waitcnt vmcnt(0)" ::: "memory");  // h stores at LLC
        __syncthreads();                                   // whole block drained
        if (tid == 0) {
            __hip_atomic_fetch_add(&bar[(g * 8 + sub) * 32], 1u,
                                   __ATOMIC_RELAXED, __HIP_MEMORY_SCOPE_AGENT);
            const unsigned int target = (unsigned int)(t + 1) * BPG;
            unsigned int miss = 0;
            for (;;) {
                unsigned int s = 0;
#pragma unroll
                for (int i = 0; i < 8; ++i)
                    s += __hip_atomic_load(&bar[(g * 8 + i) * 32],
                                           __ATOMIC_RELAXED, __HIP_MEMORY_SCOPE_AGENT);
                if (s >= target) break;
                if (++miss > (1u << 20)) break;  // bounded: never hang the GPU
                __builtin_amdgcn_s_sleep(1);
            }
        }
        __syncthreads();
    }
}

extern "C" void kernel_launch(void* const* d_in, const int* in_sizes, int n_in,
                              void* d_out, int out_size, void* d_ws, size_t ws_size,
                              hipStream_t stream) {
    const float* seqs = (const float*)d_in[0];
    const float* h0   = (const float*)d_in[1];
    const float* c0   = (const float*)d_in[2];
    const float* Wi   = (const float*)d_in[3];
    const float* bi   = (const float*)d_in[4];
    const float* Wf   = (const float*)d_in[5];
    const float* bf   = (const float*)d_in[6];
    const float* Wg   = (const float*)d_in[7];
    const float* bg   = (const float*)d_in[8];
    const float* Wo   = (const float*)d_in[9];
    const float* bo   = (const float*)d_in[10];
    float* out = (float*)d_out;
    unsigned int* bar = (unsigned int*)d_ws;

    // zero barrier counters every launch (deterministic across graph replays)
    hipMemsetAsync(bar, 0, 4 * 8 * 32 * sizeof(unsigned int), stream);

    hipLaunchKernelGGL(lstm_persistent, dim3(256), dim3(256), 0, stream,
                       seqs, h0, c0, Wi, bi, Wf, bf, Wg, bg, Wo, bo, out, bar);
}

// Round 5
// 5817.137 us; speedup vs baseline: 4.1588x; 1.0543x over previous
//
#include <hip/hip_runtime.h>

// LSTM scan, persistent, BARRIER-FREE. T=512, B=64, D=256, H=512, K=768.
// 4 groups x 64 blocks; group g owns batches [16g,16g+16); block owns 8 units.
// Weights register-resident: thread holds 4 rows x 48 cols (halves LDS-pipe
// load vs R4's 2x96 — LDS was the matmul bottleneck: 9216cy/CU vs 3072 VALU).
// Sync: h stores write-through to LLC (sc0 sc1); consumers POLL THE H DATA
// for a poison pattern (h in (-1,1) can never be 0x7f7f7f7f). out[1..T] is
// poisoned by hipMemsetAsync each launch; each h[t] written exactly once.
// No barrier, no flags, no atomics, no drains: ~1.5-2 LLC RTT per step and
// block skew pipelines instead of being maxed.

#define TSTEPS 512
#define BATCH 64
#define DIN 256
#define HID 512
#define KTOT (HID + DIN)     // 768
#define BPB 16               // batches per group
#define UPB 8                // units per block
#define VSTRIDE 772          // padded floats per v row
#define RSTRIDE 17           // padded batch dim for reduction buffer
#define POISON 0x7f7f7f7fu   // 3.39e38f — unreachable for h in (-1,1)

// LLC-coherent ops: bypass L1 and non-coherent per-XCD L2.
__device__ __forceinline__ float4 llc_load4(const float* p) {
    float4 r;
    asm volatile("global_load_dwordx4 %0, %1, off sc0 sc1" : "=v"(r) : "v"(p));
    return r;
}
__device__ __forceinline__ void llc_store1(float* p, float v) {
    asm volatile("global_store_dword %0, %1, off sc0 sc1" :: "v"(p), "v"(v) : "memory");
}

__global__ __launch_bounds__(256, 1)
void lstm_persistent(const float* __restrict__ seqs,
                     const float* __restrict__ h0,
                     const float* __restrict__ c0,
                     const float* __restrict__ Wi, const float* __restrict__ bi,
                     const float* __restrict__ Wf, const float* __restrict__ bff,
                     const float* __restrict__ Wg, const float* __restrict__ bg,
                     const float* __restrict__ Wo, const float* __restrict__ bo,
                     float* __restrict__ out)   // [T+1][B][H] then cT [B][H]
{
    __shared__ float v[BPB * VSTRIDE];            // 49408 B: [h | x] per batch
    __shared__ float red[4 * 32 * RSTRIDE];       // 8704 B
    __shared__ float c_s[UPB * BPB];              // 512 B
    __shared__ float bias_s[32];                  // 128 B

    const int tid = threadIdx.x;
    const int bid = blockIdx.x;
    const int g    = (bid & 7) >> 1;                    // group (XCD pair)
    const int rblk = ((bid & 1) << 5) | (bid >> 3);     // 0..63 within group
    const int b0 = g * BPB;
    const int u0 = rblk * UPB;

    const int rg = tid & 7;          // row group: rows 4rg..4rg+3
    const int bh = (tid >> 3) & 1;   // batch parity (batch = 2j+bh)
    const int kc = tid >> 4;         // k-chunk 0..15 (48 cols each)

    // ---- weights -> registers: 4 rows x 48 cols per thread ----
    const int m0 = 4 * rg;           // rows m0..m0+3, all in one gate (8-row gates)
    const int gate = m0 >> 3;
    const int ul0 = m0 & 7;
    const float* Wsel = (gate == 0) ? Wi : (gate == 1) ? Wf : (gate == 2) ? Wg : Wo;
    float4 w[4][12];
#pragma unroll
    for (int r = 0; r < 4; ++r) {
        const float* rp = Wsel + (size_t)(u0 + ul0 + r) * KTOT + kc * 48;
#pragma unroll
        for (int i = 0; i < 12; ++i)
            w[r][i] = reinterpret_cast<const float4*>(rp)[i];
    }

    if (tid < 32) {
        const int gg = tid >> 3, uu = tid & 7;
        const float* bsel = (gg == 0) ? bi : (gg == 1) ? bff : (gg == 2) ? bg : bo;
        bias_s[tid] = bsel[u0 + uu];
    }
    if (tid < 128) {   // c init + allhidden[0] = h0 (plain stores; never polled)
        const int uu = tid & 7, bb = tid >> 3;
        c_s[uu * BPB + bb] = c0[(size_t)(b0 + bb) * HID + u0 + uu];
        out[(size_t)(b0 + bb) * HID + u0 + uu] = h0[(size_t)(b0 + bb) * HID + u0 + uu];
    }

    // ---- preloop staging: h_0 and x_0 -> LDS (plain cached loads) ----
#pragma unroll
    for (int i = 0; i < 8; ++i) {
        const int idx = tid + i * 256;
        const int b = idx >> 7, k4 = idx & 127;
        const float4 val =
            reinterpret_cast<const float4*>(h0 + (size_t)(b0 + b) * HID)[k4];
        *reinterpret_cast<float4*>(&v[b * VSTRIDE + k4 * 4]) = val;
    }
#pragma unroll
    for (int i = 0; i < 4; ++i) {
        const int idx = tid + i * 256;
        const int b = idx >> 6, k4 = idx & 63;
        const float4 val =
            reinterpret_cast<const float4*>(seqs + (size_t)(b0 + b) * DIN)[k4];
        *reinterpret_cast<float4*>(&v[b * VSTRIDE + HID + k4 * 4]) = val;
    }

    for (int t = 0; t < TSTEPS; ++t) {
        __syncthreads();   // A: v holds (h_t, x_t); red free

        // ---- T14: issue x_{t+1} loads early; complete under the matmul ----
        float4 xreg[4];
        if (t + 1 < TSTEPS) {
            const float* xs = seqs + (size_t)(t + 1) * BATCH * DIN;
#pragma unroll
            for (int i = 0; i < 4; ++i) {
                const int idx = tid + i * 256;
                const int b = idx >> 6, k4 = idx & 63;
                xreg[i] = reinterpret_cast<const float4*>(xs + (size_t)(b0 + b) * DIN)[k4];
            }
        }

        // ---- matmul: 4 rows x 8 batches x 48 cols per thread ----
        float acc[4][8];
#pragma unroll
        for (int r = 0; r < 4; ++r)
#pragma unroll
            for (int j = 0; j < 8; ++j) acc[r][j] = 0.f;
#pragma unroll
        for (int i4 = 0; i4 < 12; ++i4) {
#pragma unroll
            for (int j = 0; j < 8; ++j) {
                const float4 vv = *reinterpret_cast<const float4*>(
                    &v[(2 * j + bh) * VSTRIDE + kc * 48 + i4 * 4]);
#pragma unroll
                for (int r = 0; r < 4; ++r) {
                    acc[r][j] = fmaf(w[r][i4].x, vv.x, acc[r][j]);
                    acc[r][j] = fmaf(w[r][i4].y, vv.y, acc[r][j]);
                    acc[r][j] = fmaf(w[r][i4].z, vv.z, acc[r][j]);
                    acc[r][j] = fmaf(w[r][i4].w, vv.w, acc[r][j]);
                }
            }
        }

        // ---- reduce kc: lane bits 4,5 in-wave, 4 wave-partials via LDS ----
#pragma unroll
        for (int r = 0; r < 4; ++r)
#pragma unroll
            for (int j = 0; j < 8; ++j) {
                acc[r][j] += __shfl_xor(acc[r][j], 16);
                acc[r][j] += __shfl_xor(acc[r][j], 32);
            }
        if ((tid & 63) < 16) {
            const int w4 = tid >> 6;   // wave id = kc high bits
#pragma unroll
            for (int r = 0; r < 4; ++r)
#pragma unroll
                for (int j = 0; j < 8; ++j)
                    red[(w4 * 32 + m0 + r) * RSTRIDE + 2 * j + bh] = acc[r][j];
        }
        __syncthreads();   // B: red ready; v free for restage

        // ---- elementwise + write-through h store (BEFORE poll: no self-wait) ----
        if (tid < 128) {
            const int uu = tid & 7, bb = tid >> 3;
            float gi = bias_s[uu], gf = bias_s[8 + uu],
                  gG = bias_s[16 + uu], go = bias_s[24 + uu];
#pragma unroll
            for (int w4 = 0; w4 < 4; ++w4) {
                gi += red[(w4 * 32 + uu) * RSTRIDE + bb];
                gf += red[(w4 * 32 + 8 + uu) * RSTRIDE + bb];
                gG += red[(w4 * 32 + 16 + uu) * RSTRIDE + bb];
                go += red[(w4 * 32 + 24 + uu) * RSTRIDE + bb];
            }
            const float i_ = 1.f / (1.f + __expf(-gi));
            const float f_ = 1.f / (1.f + __expf(-gf));
            const float o_ = 1.f / (1.f + __expf(-go));
            float eg = __expf(-2.f * fabsf(gG));
            float tg = (1.f - eg) / (1.f + eg);
            tg = (gG < 0.f) ? -tg : tg;
            const float cn = f_ * c_s[uu * BPB + bb] + i_ * tg;
            c_s[uu * BPB + bb] = cn;
            float ec = __expf(-2.f * fabsf(cn));
            float tc = (1.f - ec) / (1.f + ec);
            tc = (cn < 0.f) ? -tc : tc;
            const float hn = o_ * tc;
            llc_store1(out + (size_t)(t + 1) * BATCH * HID + (size_t)(b0 + bb) * HID + u0 + uu, hn);
            if (t == TSTEPS - 1)
                out[(size_t)(TSTEPS + 1) * BATCH * HID + (size_t)(b0 + bb) * HID + u0 + uu] = cn;
        }

        if (t + 1 < TSTEPS) {
            // ---- x_{t+1} regs -> LDS (loads completed during matmul) ----
#pragma unroll
            for (int i = 0; i < 4; ++i) {
                const int idx = tid + i * 256;
                const int b = idx >> 6, k4 = idx & 63;
                *reinterpret_cast<float4*>(&v[b * VSTRIDE + HID + k4 * 4]) = xreg[i];
            }
            // ---- poll + stage h_{t+1}: data IS the barrier ----
            const float* hn = out + (size_t)(t + 1) * BATCH * HID;
            const float* pp[8];
            int lb[8];
#pragma unroll
            for (int i = 0; i < 8; ++i) {
                const int idx = tid + i * 256;
                const int b = idx >> 7, k4 = idx & 127;
                pp[i] = hn + (size_t)(b0 + b) * HID + k4 * 4;
                lb[i] = b * VSTRIDE + k4 * 4;
            }
            float4 hb[8];
            unsigned miss = 0;
            for (;;) {
#pragma unroll
                for (int i = 0; i < 8; ++i) hb[i] = llc_load4(pp[i]);
                asm volatile("s_waitcnt vmcnt(0)" ::: "memory");
                __builtin_amdgcn_sched_barrier(0);
                bool ok = true;
#pragma unroll
                for (int i = 0; i < 8; ++i) {
                    ok &= (__float_as_uint(hb[i].x) != POISON);
                    ok &= (__float_as_uint(hb[i].y) != POISON);
                    ok &= (__float_as_uint(hb[i].z) != POISON);
                    ok &= (__float_as_uint(hb[i].w) != POISON);
                }
                if (ok) break;
                if (++miss > (1u << 18)) break;   // bounded: never hang the GPU
                __builtin_amdgcn_s_sleep(1);
            }
#pragma unroll
            for (int i = 0; i < 8; ++i)
                *reinterpret_cast<float4*>(&v[lb[i]]) = hb[i];
        }
    }
}

extern "C" void kernel_launch(void* const* d_in, const int* in_sizes, int n_in,
                              void* d_out, int out_size, void* d_ws, size_t ws_size,
                              hipStream_t stream) {
    const float* seqs = (const float*)d_in[0];
    const float* h0   = (const float*)d_in[1];
    const float* c0   = (const float*)d_in[2];
    const float* Wi   = (const float*)d_in[3];
    const float* bi   = (const float*)d_in[4];
    const float* Wf   = (const float*)d_in[5];
    const float* bf   = (const float*)d_in[6];
    const float* Wg   = (const float*)d_in[7];
    const float* bg   = (const float*)d_in[8];
    const float* Wo   = (const float*)d_in[9];
    const float* bo   = (const float*)d_in[10];
    float* out = (float*)d_out;

    // Poison h[1..T] every launch: each h[t][b][u] is written exactly once per
    // run, so this makes the data itself the readiness flag (replay-safe).
    hipMemsetAsync((char*)out + (size_t)BATCH * HID * 4, 0x7f,
                   (size_t)TSTEPS * BATCH * HID * 4, stream);

    hipLaunchKernelGGL(lstm_persistent, dim3(256), dim3(256), 0, stream,
                       seqs, h0, c0, Wi, bi, Wf, bf, Wg, bg, Wo, bo, out);
}